// Round 8
// baseline (3196.052 us; speedup 1.0000x reference)
//
#include <hip/hip_runtime.h>

#define Bn 32
#define Tn 2048
#define Hn 256
#define DEPTHn 4

typedef unsigned short u16;
typedef u16    us8 __attribute__((ext_vector_type(8)));
typedef _Float16 h8 __attribute__((ext_vector_type(8)));
typedef float  f4  __attribute__((ext_vector_type(4)));

__device__ __forceinline__ u16 f2h(float x) {
    return __builtin_bit_cast(u16, (_Float16)x);
}

// ---------------------------------------------------------------------------
// Phase A: Z[b,t,:] = in[b,t,:] @ Wx + bias. Register-tiled 8x8 fp32.
// (unchanged — known good, ~110 µs per dispatch)
// ---------------------------------------------------------------------------
#define GR 64
__global__ __launch_bounds__(256, 2) void gemm_xw(
    const float* __restrict__ in, long in_bstride,
    const float* __restrict__ Wx, const float* __restrict__ bias,
    float* __restrict__ Z)
{
    __shared__ __align__(16) float a_lds[GR][264];

    const int tid = threadIdx.x;
    const int row0 = blockIdx.x * GR;

    #pragma unroll
    for (int q = 0; q < 16; ++q) {
        int f = tid + q * 256;
        int r  = f >> 6;
        int c4 = f & 63;
        int grow = row0 + r;
        int b = grow >> 11;
        int t = grow & (Tn - 1);
        float4 v = *(const float4*)(in + (long)b * in_bstride + (long)t * Hn + c4 * 4);
        *(float4*)(&a_lds[r][c4 * 4]) = v;
    }
    __syncthreads();

    const int g  = tid >> 5;
    const int cg = tid & 31;

    float acc[8][8];
    #pragma unroll
    for (int i = 0; i < 8; ++i)
        #pragma unroll
        for (int j = 0; j < 8; ++j) acc[i][j] = 0.f;

    for (int k4 = 0; k4 < 64; ++k4) {
        float4 w[4][2];
        #pragma unroll
        for (int kk = 0; kk < 4; ++kk) {
            const float* wr = Wx + (long)(k4 * 4 + kk) * Hn + cg * 8;
            w[kk][0] = *(const float4*)(wr);
            w[kk][1] = *(const float4*)(wr + 4);
        }
        float4 a[8];
        #pragma unroll
        for (int i = 0; i < 8; ++i)
            a[i] = *(const float4*)(&a_lds[i * 8 + g][k4 * 4]);

        #pragma unroll
        for (int i = 0; i < 8; ++i) {
            #pragma unroll
            for (int kk = 0; kk < 4; ++kk) {
                float av = ((const float*)&a[i])[kk];
                acc[i][0] = fmaf(av, w[kk][0].x, acc[i][0]);
                acc[i][1] = fmaf(av, w[kk][0].y, acc[i][1]);
                acc[i][2] = fmaf(av, w[kk][0].z, acc[i][2]);
                acc[i][3] = fmaf(av, w[kk][0].w, acc[i][3]);
                acc[i][4] = fmaf(av, w[kk][1].x, acc[i][4]);
                acc[i][5] = fmaf(av, w[kk][1].y, acc[i][5]);
                acc[i][6] = fmaf(av, w[kk][1].z, acc[i][6]);
                acc[i][7] = fmaf(av, w[kk][1].w, acc[i][7]);
            }
        }
    }

    float4 b0 = *(const float4*)(bias + cg * 8);
    float4 b1 = *(const float4*)(bias + cg * 8 + 4);
    #pragma unroll
    for (int i = 0; i < 8; ++i) {
        long row = row0 + i * 8 + g;
        float4 o0 = { acc[i][0] + b0.x, acc[i][1] + b0.y, acc[i][2] + b0.z, acc[i][3] + b0.w };
        float4 o1 = { acc[i][4] + b1.x, acc[i][5] + b1.y, acc[i][6] + b1.z, acc[i][7] + b1.w };
        *(float4*)(Z + row * Hn + cg * 8)     = o0;
        *(float4*)(Z + row * Hn + cg * 8 + 4) = o1;
    }
}

// ---------------------------------------------------------------------------
// Phase B: h_t = tanh(Z[t] + h_{t-d} @ Wh) per stream (b, r) — MFMA version.
// 256 threads = 4 waves. Wave wv owns channels [64wv, 64wv+64) as 4 blocks of
// 16 cols; per block, K=256 via 8 chained mfma_f32_16x16x32_f16 (2 acc chains
// of 4, f32 accumulate). Wh (f16) lives permanently in 128 VGPR/lane.
// A trick (M=1): each 16-lane group broadcast-reads h chunk bytes
// [64cc + 16g, +16) — every A row holds the same chunk, rows are independent
// in C = A*B, and we consume only C row 0 = reg 0 of lanes 0..15
// (C layout col=lane&15, row=(lane>>4)*4+reg — HW-verified mapping).
// Per step per wave: 8 bcast ds_read_b128 + 32 MFMA + tanh(4) + 4 ds_write_b16.
// Sync: fused "s_waitcnt lgkmcnt(0); s_barrier" (proven R6/R7); z prefetch
// loads and output stores stay in flight across steps.
// ---------------------------------------------------------------------------
__global__ __launch_bounds__(256) void rnn_layer(
    const float* __restrict__ Z,
    const float* __restrict__ Wh,       // [256,256] this layer, fp32
    float* __restrict__ out,            // d_out + j*Tn*Hn; batch stride DEPTHn*Tn*Hn
    const int* __restrict__ seq_lens,
    int dilation)
{
    __shared__ __align__(16) u16 hb[2][256];   // f16 h, double buffered

    const int tid  = threadIdx.x;
    const int wv   = tid >> 6;          // 0..3
    const int lane = tid & 63;
    const int g    = lane >> 4;         // 0..3 (A k-subchunk group)
    const int c    = lane & 15;         // col within 16-block

    const int s = blockIdx.x;
    const int b = s / dilation;
    const int r = s % dilation;

    // B fragments: block j covers cols 64wv+16j+[0,16); chunk cc covers
    // k in [32cc, 32cc+32). Lane holds B[k = 32cc+8g+i][col = 64wv+16j+c].
    us8 Bf[4][8];
    #pragma unroll
    for (int j = 0; j < 4; ++j) {
        #pragma unroll
        for (int cc = 0; cc < 8; ++cc) {
            const float* wp = Wh + (long)(32 * cc + 8 * g) * Hn + (64 * wv + 16 * j + c);
            us8 v;
            #pragma unroll
            for (int i = 0; i < 8; ++i) v[i] = f2h(wp[(long)i * Hn]);
            Bf[j][cc] = v;
        }
    }

    hb[0][tid] = 0;                      // zero initial h (tid covers all 256)
    const int L = seq_lens[b];
    __syncthreads();

    const float* zb = Z + (long)b * Tn * Hn;
    float* ob = out + (long)b * (DEPTHn * Tn * Hn);

    int cur = 0;
    float z1[4], z2[4];
    if (g == 0) {
        #pragma unroll
        for (int j = 0; j < 4; ++j) {
            int ch = 64 * wv + 16 * j + c;
            z1[j] = zb[(long)r * Hn + ch];
            z2[j] = (r + dilation < Tn) ? zb[(long)(r + dilation) * Hn + ch] : 0.f;
        }
    }

    for (int t = r; t < Tn; t += dilation) {
        float zc[4];
        #pragma unroll
        for (int j = 0; j < 4; ++j) { zc[j] = z1[j]; z1[j] = z2[j]; }
        int t2 = t + 2 * dilation;
        if (g == 0 && t2 < Tn) {
            #pragma unroll
            for (int j = 0; j < 4; ++j)
                z2[j] = zb[(long)t2 * Hn + 64 * wv + 16 * j + c];   // depth-2 prefetch
        }

        const u16* hp = hb[cur];
        f4 zero = { 0.f, 0.f, 0.f, 0.f };
        f4 acc[4][2];
        #pragma unroll
        for (int j = 0; j < 4; ++j) { acc[j][0] = zero; acc[j][1] = zero; }

        #pragma unroll
        for (int cc = 0; cc < 8; ++cc) {
            // broadcast read: all 16 lanes of group g read the same 16B
            us8 av_ = *(const us8*)(hp + 32 * cc + 8 * g);
            h8 av = __builtin_bit_cast(h8, av_);
            #pragma unroll
            for (int j = 0; j < 4; ++j)
                acc[j][cc & 1] = __builtin_amdgcn_mfma_f32_16x16x32_f16(
                    av, __builtin_bit_cast(h8, Bf[j][cc]), acc[j][cc & 1], 0, 0, 0);
        }

        if (g == 0) {                    // lanes 0..15 hold C row 0 in reg 0
            #pragma unroll
            for (int j = 0; j < 4; ++j) {
                float y = acc[j][0][0] + acc[j][1][0] + zc[j];
                float e = __expf(2.f * y);               // saturates at +/-inf
                float hn = 1.f - 2.f / (e + 1.f);
                int ch = 64 * wv + 16 * j + c;
                ob[(long)t * Hn + ch] = (t < L) ? hn : 0.f;   // masked, in flight
                hb[cur ^ 1][ch] = f2h(hn);                    // ds_write_b16
            }
        }

        // fused LDS-drain + barrier: one opaque memory op, nothing crosses it
        asm volatile("s_waitcnt lgkmcnt(0)\n\ts_barrier" ::: "memory");
        cur ^= 1;
    }
}

// ---------------------------------------------------------------------------
extern "C" void kernel_launch(void* const* d_in, const int* in_sizes, int n_in,
                              void* d_out, int out_size, void* d_ws, size_t ws_size,
                              hipStream_t stream) {
    const float* x    = (const float*)d_in[0];   // [B,T,H]
    const float* Wx   = (const float*)d_in[1];   // [4,H,H]
    const float* Wh   = (const float*)d_in[2];   // [4,H,H]
    const float* bias = (const float*)d_in[3];   // [4,H]
    const int*   seq  = (const int*)  d_in[4];   // [B]
    float* out = (float*)d_out;                  // [B,4,T,H]
    float* Z   = (float*)d_ws;                   // [B,T,H] scratch (64 MB)

    for (int j = 0; j < DEPTHn; ++j) {
        const float* in;
        long bstride;
        if (j == 0) { in = x;                             bstride = (long)Tn * Hn; }
        else        { in = out + (long)(j - 1) * Tn * Hn; bstride = (long)DEPTHn * Tn * Hn; }

        hipLaunchKernelGGL(gemm_xw, dim3(Bn * Tn / GR), dim3(256), 0, stream,
                           in, bstride, Wx + (long)j * Hn * Hn, bias + (long)j * Hn, Z);

        int d = 1 << j;
        hipLaunchKernelGGL(rnn_layer, dim3(Bn * d), dim3(256), 0, stream,
                           Z, Wh + (long)j * Hn * Hn, out + (long)j * Tn * Hn, seq, d);
    }
}